// Round 19
// baseline (43.611 us; speedup 1.0000x reference)
//
#include <hip/hip_runtime.h>

// CenterNeighAtt on MI355X. E=512, F=256, R=4.
//
// Exact math simplifications (validated R1-R18, absmax ~5e-4 vs 2.3e-3 threshold):
//  * alpha = softmax_j(sum_i scores[i,j]) is uniform 1/E: sum_i attention[i,j,f]==1,
//    so column sums of scores are constant in j. lin_w/lin_b are dead inputs.
//  * No max-subtraction in softmaxes: logits bounded (~20), exp far below f32 overflow.
//  * s[i,j]>0 (softmax) => lrelu(s*q) = s*lrelu(q); P/N lrelu halves hoisted per row.
//
// Structure lessons (measured):
//  * Cross-grid sync / __threadfence in-dispatch: toxic (R3/R5/R6/R7). 3 stream
//    dispatches is the proven minimum (Z is a full-axis softmax reduction).
//  * Plateau 36.8-39 across: VALU-20% (R17), LDS->0 (R18), traffic/2 (R15),
//    occupancy x2 (R13), block size (R16), packed math (R9/R14). All throughput
//    resources ruled out -> surviving hypothesis: vmem latency under-coverage.
//  * Rule #20: tiny fully-unrolled arrays only. No VOP3P asm (R10).
//
// R19 = R18 + explicit 2-stage register prefetch of the h / {h,g} vmem streams
// (full static unroll): every body's load is in flight one body ahead.

typedef float f2 __attribute__((ext_vector_type(2)));

#define EE 512
#define FF 256
#define RRR 4
#define LOG2E 1.44269504088896340736f
#define TPB 1024   // threads per block
#define RPB 4      // rows per block
#define NT 16      // wave-teams (64-wide)
#define CH 32      // chunk length (512/16)
#define FB 64      // f per block

// --- kA: s[i,:] = softmax_j(sum_r adj[r,i,:]); alpha -----------------------
__global__ __launch_bounds__(256) void kA(const float* __restrict__ adj,
                                          float* __restrict__ s,
                                          float* __restrict__ out) {
    const int i = blockIdx.x;
    const int t = threadIdx.x;
    if (i == 0) {   // alpha: softmax of a constant vector = uniform 1/E
        out[EE * FF + t]       = 1.0f / EE;
        out[EE * FF + 256 + t] = 1.0f / EE;
    }
    const float* base = adj + (size_t)i * EE;
    float t0 = 0.f, t1 = 0.f;
#pragma unroll
    for (int r = 0; r < RRR; ++r) {
        t0 += base[(size_t)r * EE * EE + t];
        t1 += base[(size_t)r * EE * EE + t + 256];
    }
    const float e0 = __expf(t0);
    const float e1 = __expf(t1);
    __shared__ float red[256];
    red[t] = e0 + e1;
    __syncthreads();
    for (int off = 128; off > 0; off >>= 1) {
        if (t < off) red[t] += red[t + off];
        __syncthreads();
    }
    const float inv = 1.0f / red[0];
    s[(size_t)i * EE + t]       = e0 * inv;
    s[(size_t)i * EE + t + 256] = e1 * inv;
}

// --- kB: Z[j,f] = sum_i exp2(s[i,j]*lrelu(h_if*h_jf)*log2e);
//         hg[j,f] = {h[j,f], h[j,f]*rcp(Z)} --------------------------------
__global__ __launch_bounds__(TPB, 8) void kB(const float* __restrict__ h,
                                             const float* __restrict__ s,
                                             f2* __restrict__ hg) {
    const int tid = threadIdx.x;
    const int fl  = tid & (FB - 1);                            // 0..63 (lane)
    const int team = __builtin_amdgcn_readfirstlane(tid >> 6); // wave-uniform
    const int j0  = blockIdx.x * RPB;
    const int f   = blockIdx.y * FB + fl;
    __shared__ float ps[NT * RPB * FB];   // 16 KB team-reduce
    const float hj0 = h[(size_t)(j0 + 0) * FF + f] * LOG2E;
    const float hj1 = h[(size_t)(j0 + 1) * FF + f] * LOG2E;
    const float hj2 = h[(size_t)(j0 + 2) * FF + f] * LOG2E;
    const float hj3 = h[(size_t)(j0 + 3) * FF + f] * LOG2E;
    const float P0 = fmaxf(hj0, 0.2f * hj0), N0 = fminf(hj0, 0.2f * hj0);
    const float P1 = fmaxf(hj1, 0.2f * hj1), N1 = fminf(hj1, 0.2f * hj1);
    const float P2 = fmaxf(hj2, 0.2f * hj2), N2 = fminf(hj2, 0.2f * hj2);
    const float P3 = fmaxf(hj3, 0.2f * hj3), N3 = fminf(hj3, 0.2f * hj3);
    float Z0 = 0.f, Z1 = 0.f, Z2 = 0.f, Z3 = 0.f;
    const float* hp = h + (size_t)(team * CH) * FF + f;
    const float* sp = s + (size_t)(team * CH) * EE + j0;   // uniform address
    float hcur = hp[0];                    // prefetch stage 0
#pragma unroll
    for (int ii = 0; ii < CH; ++ii) {
        const float hnext = (ii + 1 < CH) ? hp[(size_t)(ii + 1) * FF] : 0.f; // in flight
        const float s0 = sp[(size_t)ii * EE + 0];   // wave-uniform -> s_load
        const float s1 = sp[(size_t)ii * EE + 1];
        const float s2 = sp[(size_t)ii * EE + 2];
        const float s3 = sp[(size_t)ii * EE + 3];
        const bool pos = hcur > 0.f;
        const float y0 = s0 * ((pos ? P0 : N0) * hcur);
        const float y1 = s1 * ((pos ? P1 : N1) * hcur);
        const float y2 = s2 * ((pos ? P2 : N2) * hcur);
        const float y3 = s3 * ((pos ? P3 : N3) * hcur);
        Z0 += __builtin_amdgcn_exp2f(y0);
        Z1 += __builtin_amdgcn_exp2f(y1);
        Z2 += __builtin_amdgcn_exp2f(y2);
        Z3 += __builtin_amdgcn_exp2f(y3);
        hcur = hnext;
    }
    ps[(team * RPB + 0) * FB + fl] = Z0;
    ps[(team * RPB + 1) * FB + fl] = Z1;
    ps[(team * RPB + 2) * FB + fl] = Z2;
    ps[(team * RPB + 3) * FB + fl] = Z3;
    __syncthreads();
    if (tid < RPB * FB) {                          // 256 outputs
        const int r = tid >> 6, fq = tid & (FB - 1);
        float Zt = 0.f;
#pragma unroll
        for (int t = 0; t < NT; ++t) Zt += ps[(t * RPB + r) * FB + fq];
        const size_t o = (size_t)(j0 + r) * FF + blockIdx.y * FB + fq;
        const float hv = h[o];
        hg[o] = (f2){hv, hv * __builtin_amdgcn_rcpf(Zt)};
    }
}

// --- kC: out[i,f] = elu(sum_j g[j,f]*exp2(s[i,j]*lrelu(h_if*h_jf)*log2e)) --
__global__ __launch_bounds__(TPB, 8) void kC(const float* __restrict__ h,
                                             const float* __restrict__ s,
                                             const f2* __restrict__ hg,
                                             float* __restrict__ out) {
    const int tid = threadIdx.x;
    const int fl  = tid & (FB - 1);
    const int team = __builtin_amdgcn_readfirstlane(tid >> 6); // wave-uniform
    const int i0  = blockIdx.x * RPB;
    const int f   = blockIdx.y * FB + fl;
    __shared__ float ps[NT * RPB * FB];
    const float hl0 = h[(size_t)(i0 + 0) * FF + f] * LOG2E;
    const float hl1 = h[(size_t)(i0 + 1) * FF + f] * LOG2E;
    const float hl2 = h[(size_t)(i0 + 2) * FF + f] * LOG2E;
    const float hl3 = h[(size_t)(i0 + 3) * FF + f] * LOG2E;
    const float P0 = fmaxf(hl0, 0.2f * hl0), N0 = fminf(hl0, 0.2f * hl0);
    const float P1 = fmaxf(hl1, 0.2f * hl1), N1 = fminf(hl1, 0.2f * hl1);
    const float P2 = fmaxf(hl2, 0.2f * hl2), N2 = fminf(hl2, 0.2f * hl2);
    const float P3 = fmaxf(hl3, 0.2f * hl3), N3 = fminf(hl3, 0.2f * hl3);
    float a0 = 0.f, a1 = 0.f, a2 = 0.f, a3 = 0.f;
    const f2* hgp = hg + (size_t)(team * CH) * FF + f;
    const float* sp = s + (size_t)i0 * EE + team * CH;      // uniform address
    f2 hgcur = hgp[0];                     // prefetch stage 0
#pragma unroll
    for (int jj = 0; jj < CH; ++jj) {
        const f2 hgnext = (jj + 1 < CH) ? hgp[(size_t)(jj + 1) * FF]
                                        : (f2){0.f, 0.f};    // in flight
        const float s0 = sp[jj];                   // wave-uniform -> s_load
        const float s1 = sp[EE + jj];
        const float s2 = sp[2 * EE + jj];
        const float s3 = sp[3 * EE + jj];
        const bool pos = hgcur.x > 0.f;
        const float y0 = s0 * ((pos ? P0 : N0) * hgcur.x);
        const float y1 = s1 * ((pos ? P1 : N1) * hgcur.x);
        const float y2 = s2 * ((pos ? P2 : N2) * hgcur.x);
        const float y3 = s3 * ((pos ? P3 : N3) * hgcur.x);
        a0 = fmaf(__builtin_amdgcn_exp2f(y0), hgcur.y, a0);
        a1 = fmaf(__builtin_amdgcn_exp2f(y1), hgcur.y, a1);
        a2 = fmaf(__builtin_amdgcn_exp2f(y2), hgcur.y, a2);
        a3 = fmaf(__builtin_amdgcn_exp2f(y3), hgcur.y, a3);
        hgcur = hgnext;
    }
    ps[(team * RPB + 0) * FB + fl] = a0;
    ps[(team * RPB + 1) * FB + fl] = a1;
    ps[(team * RPB + 2) * FB + fl] = a2;
    ps[(team * RPB + 3) * FB + fl] = a3;
    __syncthreads();
    if (tid < RPB * FB) {
        const int r = tid >> 6, fq = tid & (FB - 1);
        float a = 0.f;
#pragma unroll
        for (int t = 0; t < NT; ++t) a += ps[(t * RPB + r) * FB + fq];
        out[(size_t)(i0 + r) * FF + blockIdx.y * FB + fq] =
            (a > 0.f) ? a : (__expf(a) - 1.0f);
    }
}

extern "C" void kernel_launch(void* const* d_in, const int* in_sizes, int n_in,
                              void* d_out, int out_size, void* d_ws, size_t ws_size,
                              hipStream_t stream) {
    const float* h   = (const float*)d_in[0];  // [E,F]
    const float* adj = (const float*)d_in[1];  // [R,E,E]
    // lin_w / lin_b mathematically dead (alpha uniform).

    float* s   = (float*)d_ws;                 // 1 MB
    f2*    hg  = (f2*)(s + (size_t)EE * EE);   // 1 MB (total 2 MB)
    float* out = (float*)d_out;

    kA<<<EE, 256, 0, stream>>>(adj, s, out);
    kB<<<dim3(EE / RPB, FF / FB), TPB, 0, stream>>>(h, s, hg);
    kC<<<dim3(EE / RPB, FF / FB), TPB, 0, stream>>>(h, s, hg, out);
}

// Round 20
// 36.780 us; speedup vs baseline: 1.1857x; 1.1857x over previous
//
#include <hip/hip_runtime.h>

// CenterNeighAtt on MI355X. E=512, F=256, R=4.
//
// Exact math simplifications (validated R1-R18, absmax ~5e-4 vs 2.3e-3 threshold):
//  * alpha = softmax_j(sum_i scores[i,j]) is uniform 1/E: sum_i attention[i,j,f]==1,
//    so column sums of scores are constant in j. lin_w/lin_b are dead inputs.
//  * No max-subtraction in softmaxes: logits bounded (~20), exp far below f32 overflow.
//  * s[i,j]>0 (softmax output) => lrelu(s*q) = s*lrelu(q); lrelu halves P/N hoisted
//    per row (R17, validated).
//
// Structure lessons (measured):
//  * Cross-grid sync / __threadfence in-dispatch: toxic (R3/R5/R6/R7). Kernel
//    boundaries + plain stores ONLY. Per-dispatch gap ~3us.
//  * Plateau 36.8-39 across: VALU-20% (R17), LDS->0 (R18), traffic/2 (R15),
//    occupancy x2 (R13), block size (R16), packed math (R9/R14), manual
//    prefetch REGRESSED -6.8 (R19, Common-mistake #5). This is the floor.
//  * Rule #20: tiny fully-unrolled arrays only. No VOP3P asm (R10).
//
// R20 = R18 verbatim (best measured: 36.8us). s is wave-uniform -> 64-wide
// wave-aligned teams make the s-address scalar (s_load via scalar cache); no
// LDS staging in heavy kernels; LDS only for the 16KB team-reduce.

typedef float f2 __attribute__((ext_vector_type(2)));

#define EE 512
#define FF 256
#define RRR 4
#define LOG2E 1.44269504088896340736f
#define TPB 1024   // threads per block
#define RPB 4      // rows per block
#define NT 16      // wave-teams (64-wide)
#define CH 32      // chunk length (512/16)
#define FB 64      // f per block

// --- kA: s[i,:] = softmax_j(sum_r adj[r,i,:]); alpha -----------------------
__global__ __launch_bounds__(256) void kA(const float* __restrict__ adj,
                                          float* __restrict__ s,
                                          float* __restrict__ out) {
    const int i = blockIdx.x;
    const int t = threadIdx.x;
    if (i == 0) {   // alpha: softmax of a constant vector = uniform 1/E
        out[EE * FF + t]       = 1.0f / EE;
        out[EE * FF + 256 + t] = 1.0f / EE;
    }
    const float* base = adj + (size_t)i * EE;
    float t0 = 0.f, t1 = 0.f;
#pragma unroll
    for (int r = 0; r < RRR; ++r) {
        t0 += base[(size_t)r * EE * EE + t];
        t1 += base[(size_t)r * EE * EE + t + 256];
    }
    const float e0 = __expf(t0);
    const float e1 = __expf(t1);
    __shared__ float red[256];
    red[t] = e0 + e1;
    __syncthreads();
    for (int off = 128; off > 0; off >>= 1) {
        if (t < off) red[t] += red[t + off];
        __syncthreads();
    }
    const float inv = 1.0f / red[0];
    s[(size_t)i * EE + t]       = e0 * inv;
    s[(size_t)i * EE + t + 256] = e1 * inv;
}

// --- kB: Z[j,f] = sum_i exp2(s[i,j]*lrelu(h_if*h_jf)*log2e);
//         hg[j,f] = {h[j,f], h[j,f]*rcp(Z)} --------------------------------
__global__ __launch_bounds__(TPB, 8) void kB(const float* __restrict__ h,
                                             const float* __restrict__ s,
                                             f2* __restrict__ hg) {
    const int tid = threadIdx.x;
    const int fl  = tid & (FB - 1);                            // 0..63 (lane)
    const int team = __builtin_amdgcn_readfirstlane(tid >> 6); // wave-uniform
    const int j0  = blockIdx.x * RPB;
    const int f   = blockIdx.y * FB + fl;
    __shared__ float ps[NT * RPB * FB];   // 16 KB team-reduce
    // hoisted per-row lrelu halves (log2e folded; sign-preserving)
    const float hj0 = h[(size_t)(j0 + 0) * FF + f] * LOG2E;
    const float hj1 = h[(size_t)(j0 + 1) * FF + f] * LOG2E;
    const float hj2 = h[(size_t)(j0 + 2) * FF + f] * LOG2E;
    const float hj3 = h[(size_t)(j0 + 3) * FF + f] * LOG2E;
    const float P0 = fmaxf(hj0, 0.2f * hj0), N0 = fminf(hj0, 0.2f * hj0);
    const float P1 = fmaxf(hj1, 0.2f * hj1), N1 = fminf(hj1, 0.2f * hj1);
    const float P2 = fmaxf(hj2, 0.2f * hj2), N2 = fminf(hj2, 0.2f * hj2);
    const float P3 = fmaxf(hj3, 0.2f * hj3), N3 = fminf(hj3, 0.2f * hj3);
    float Z0 = 0.f, Z1 = 0.f, Z2 = 0.f, Z3 = 0.f;
    const float* hp = h + (size_t)(team * CH) * FF + f;
    const float* sp = s + (size_t)(team * CH) * EE + j0;   // uniform address
#pragma unroll 4
    for (int ii = 0; ii < CH; ++ii) {
        const float hif = hp[(size_t)ii * FF];     // vector load, serves 4 rows
        // wave-uniform 16B: compiler emits s_load_dwordx4 (SGPRs, no LDS)
        const float s0 = sp[(size_t)ii * EE + 0];
        const float s1 = sp[(size_t)ii * EE + 1];
        const float s2 = sp[(size_t)ii * EE + 2];
        const float s3 = sp[(size_t)ii * EE + 3];
        const bool pos = hif > 0.f;                // 1 cmp serves 4 rows
        const float y0 = s0 * ((pos ? P0 : N0) * hif);
        const float y1 = s1 * ((pos ? P1 : N1) * hif);
        const float y2 = s2 * ((pos ? P2 : N2) * hif);
        const float y3 = s3 * ((pos ? P3 : N3) * hif);
        Z0 += __builtin_amdgcn_exp2f(y0);
        Z1 += __builtin_amdgcn_exp2f(y1);
        Z2 += __builtin_amdgcn_exp2f(y2);
        Z3 += __builtin_amdgcn_exp2f(y3);
    }
    ps[(team * RPB + 0) * FB + fl] = Z0;
    ps[(team * RPB + 1) * FB + fl] = Z1;
    ps[(team * RPB + 2) * FB + fl] = Z2;
    ps[(team * RPB + 3) * FB + fl] = Z3;
    __syncthreads();
    if (tid < RPB * FB) {                          // 256 outputs
        const int r = tid >> 6, fq = tid & (FB - 1);
        float Zt = 0.f;
#pragma unroll
        for (int t = 0; t < NT; ++t) Zt += ps[(t * RPB + r) * FB + fq];
        const size_t o = (size_t)(j0 + r) * FF + blockIdx.y * FB + fq;
        const float hv = h[o];
        hg[o] = (f2){hv, hv * __builtin_amdgcn_rcpf(Zt)};
    }
}

// --- kC: out[i,f] = elu(sum_j g[j,f]*exp2(s[i,j]*lrelu(h_if*h_jf)*log2e)) --
__global__ __launch_bounds__(TPB, 8) void kC(const float* __restrict__ h,
                                             const float* __restrict__ s,
                                             const f2* __restrict__ hg,
                                             float* __restrict__ out) {
    const int tid = threadIdx.x;
    const int fl  = tid & (FB - 1);
    const int team = __builtin_amdgcn_readfirstlane(tid >> 6); // wave-uniform
    const int i0  = blockIdx.x * RPB;
    const int f   = blockIdx.y * FB + fl;
    __shared__ float ps[NT * RPB * FB];
    const float hl0 = h[(size_t)(i0 + 0) * FF + f] * LOG2E;
    const float hl1 = h[(size_t)(i0 + 1) * FF + f] * LOG2E;
    const float hl2 = h[(size_t)(i0 + 2) * FF + f] * LOG2E;
    const float hl3 = h[(size_t)(i0 + 3) * FF + f] * LOG2E;
    const float P0 = fmaxf(hl0, 0.2f * hl0), N0 = fminf(hl0, 0.2f * hl0);
    const float P1 = fmaxf(hl1, 0.2f * hl1), N1 = fminf(hl1, 0.2f * hl1);
    const float P2 = fmaxf(hl2, 0.2f * hl2), N2 = fminf(hl2, 0.2f * hl2);
    const float P3 = fmaxf(hl3, 0.2f * hl3), N3 = fminf(hl3, 0.2f * hl3);
    float a0 = 0.f, a1 = 0.f, a2 = 0.f, a3 = 0.f;
    const f2* hgp = hg + (size_t)(team * CH) * FF + f;
    const float* sp = s + (size_t)i0 * EE + team * CH;      // uniform address
#pragma unroll 4
    for (int jj = 0; jj < CH; ++jj) {
        const f2 hgv = hgp[(size_t)jj * FF];       // one dwordx2: {h_jf, g_jf}
        // 4 wave-uniform scalar loads (4 s-rows, consecutive j within a row)
        const float s0 = sp[jj];
        const float s1 = sp[EE + jj];
        const float s2 = sp[2 * EE + jj];
        const float s3 = sp[3 * EE + jj];
        const bool pos = hgv.x > 0.f;              // 1 cmp serves 4 rows
        const float y0 = s0 * ((pos ? P0 : N0) * hgv.x);
        const float y1 = s1 * ((pos ? P1 : N1) * hgv.x);
        const float y2 = s2 * ((pos ? P2 : N2) * hgv.x);
        const float y3 = s3 * ((pos ? P3 : N3) * hgv.x);
        a0 = fmaf(__builtin_amdgcn_exp2f(y0), hgv.y, a0);
        a1 = fmaf(__builtin_amdgcn_exp2f(y1), hgv.y, a1);
        a2 = fmaf(__builtin_amdgcn_exp2f(y2), hgv.y, a2);
        a3 = fmaf(__builtin_amdgcn_exp2f(y3), hgv.y, a3);
    }
    ps[(team * RPB + 0) * FB + fl] = a0;
    ps[(team * RPB + 1) * FB + fl] = a1;
    ps[(team * RPB + 2) * FB + fl] = a2;
    ps[(team * RPB + 3) * FB + fl] = a3;
    __syncthreads();
    if (tid < RPB * FB) {
        const int r = tid >> 6, fq = tid & (FB - 1);
        float a = 0.f;
#pragma unroll
        for (int t = 0; t < NT; ++t) a += ps[(t * RPB + r) * FB + fq];
        out[(size_t)(i0 + r) * FF + blockIdx.y * FB + fq] =
            (a > 0.f) ? a : (__expf(a) - 1.0f);
    }
}

extern "C" void kernel_launch(void* const* d_in, const int* in_sizes, int n_in,
                              void* d_out, int out_size, void* d_ws, size_t ws_size,
                              hipStream_t stream) {
    const float* h   = (const float*)d_in[0];  // [E,F]
    const float* adj = (const float*)d_in[1];  // [R,E,E]
    // lin_w / lin_b mathematically dead (alpha uniform).

    float* s   = (float*)d_ws;                 // 1 MB
    f2*    hg  = (f2*)(s + (size_t)EE * EE);   // 1 MB (total 2 MB)
    float* out = (float*)d_out;

    kA<<<EE, 256, 0, stream>>>(adj, s, out);
    kB<<<dim3(EE / RPB, FF / FB), TPB, 0, stream>>>(h, s, hg);
    kC<<<dim3(EE / RPB, FF / FB), TPB, 0, stream>>>(h, s, hg, out);
}